// Round 5
// baseline (206.399 us; speedup 1.0000x reference)
//
#include <hip/hip_runtime.h>

static constexpr int NXC   = 128;              // cells per axis
static constexpr int NPTS  = 100000;
static constexpr int NCH   = 8;
static constexpr int TS    = 8;                // tile cells/axis
static constexpr int NT    = 16;               // tiles/axis
static constexpr int NTILES = NT * NT * NT;    // 4096
static constexpr int REC   = 20;               // floats per particle record (5 float4)
static constexpr int CMAX  = 320;              // max candidates per block (E≈131, +16σ)
static constexpr int OMAX  = 128;              // max owned per block (E≈24)
static constexpr int PMAX  = 2560;             // max pairs per block (E≈400)

// P3M order-4 per-axis weights, x in [-1/2, 1/2]
__device__ __forceinline__ void axis_weights(float x, float w[4]) {
    float x2 = x * x, x3 = x2 * x;
    const float c = 1.0f / 48.0f;
    w[0] = c * (1.0f  - 6.0f  * x + 12.0f * x2 - 8.0f  * x3);
    w[1] = c * (23.0f - 30.0f * x - 12.0f * x2 + 24.0f * x3);
    w[2] = c * (23.0f + 30.0f * x - 12.0f * x2 - 24.0f * x3);
    w[3] = c * (1.0f  + 6.0f  * x + 12.0f * x2 + 8.0f  * x3);
}

// Mesh-scaled fractional coords (identical FP sequence in every kernel).
__device__ __forceinline__ void mesh_coords(const float* __restrict__ pos,
                                            const float* __restrict__ cell,
                                            int p, float& rx, float& ry, float& rz) {
    float a = cell[0], b = cell[1], c = cell[2];
    float d = cell[3], e = cell[4], f = cell[5];
    float g = cell[6], h = cell[7], i9 = cell[8];
    float c00 = e * i9 - f * h, c01 = f * g - d * i9, c02 = d * h - e * g;
    float c10 = c * h - b * i9, c11 = a * i9 - c * g, c12 = b * g - a * h;
    float c20 = b * f - c * e,  c21 = c * d - a * f,  c22 = a * e - b * d;
    float det = a * c00 + b * c01 + c * c02;
    float s = 128.0f / det;
    float p0 = pos[p * 3 + 0], p1 = pos[p * 3 + 1], p2 = pos[p * 3 + 2];
    rx = s * (p0 * c00 + p1 * c01 + p2 * c02);
    ry = s * (p0 * c10 + p1 * c11 + p2 * c12);
    rz = s * (p0 * c20 + p1 * c21 + p2 * c22);
}

__global__ __launch_bounds__(256) void hist_k(const float* __restrict__ pos,
                                              const float* __restrict__ cell,
                                              int* __restrict__ counts) {
    int p = blockIdx.x * 256 + threadIdx.x;
    if (p >= NPTS) return;
    float rx, ry, rz;
    mesh_coords(pos, cell, p, rx, ry, rz);
    int ix = ((int)floorf(rx)) & (NXC - 1);
    int iy = ((int)floorf(ry)) & (NXC - 1);
    int iz = ((int)floorf(rz)) & (NXC - 1);
    int tile = ((ix >> 3) * NT + (iy >> 3)) * NT + (iz >> 3);
    atomicAdd(counts + tile, 1);
}

// exclusive prefix sum over 4096 counts -> offsets[0..4096]
__global__ __launch_bounds__(256) void scan_k(const int* __restrict__ counts,
                                              int* __restrict__ offsets) {
    __shared__ int sc[256];
    int tid = threadIdx.x;
    int c[16];
    int s = 0;
    #pragma unroll
    for (int j = 0; j < 16; ++j) { c[j] = counts[tid * 16 + j]; s += c[j]; }
    sc[tid] = s;
    __syncthreads();
    for (int d = 1; d < 256; d <<= 1) {
        int v = (tid >= d) ? sc[tid - d] : 0;
        __syncthreads();
        sc[tid] += v;
        __syncthreads();
    }
    int run = sc[tid] - s;
    #pragma unroll
    for (int j = 0; j < 16; ++j) { offsets[tid * 16 + j] = run; run += c[j]; }
    if (tid == 255) offsets[NTILES] = run;
}

// Bin particles by tile; emit packed cell, original pid, and a 5-float4 record:
// [wx0..3][wy0..3][wz0..3][ch0..3][ch4..7]
__global__ __launch_bounds__(256) void reorder_k(const float* __restrict__ pos,
                                                 const float* __restrict__ pw,
                                                 const float* __restrict__ cell,
                                                 const int* __restrict__ offsets,
                                                 int* __restrict__ cursor,
                                                 int* __restrict__ scell,
                                                 int* __restrict__ spid,
                                                 float* __restrict__ srec) {
    int p = blockIdx.x * 256 + threadIdx.x;
    if (p >= NPTS) return;
    float rx, ry, rz;
    mesh_coords(pos, cell, p, rx, ry, rz);
    float fx = floorf(rx), fy = floorf(ry), fz = floorf(rz);
    int ix = ((int)fx) & (NXC - 1), iy = ((int)fy) & (NXC - 1), iz = ((int)fz) & (NXC - 1);
    int tile = ((ix >> 3) * NT + (iy >> 3)) * NT + (iz >> 3);
    int slot = atomicAdd(cursor + tile, 1);
    int idx = offsets[tile] + slot;
    scell[idx] = ix | (iy << 8) | (iz << 16);
    spid[idx] = p;
    float wx[4], wy[4], wz[4];
    axis_weights(rx - fx - 0.5f, wx);
    axis_weights(ry - fy - 0.5f, wy);
    axis_weights(rz - fz - 0.5f, wz);
    float4* r = reinterpret_cast<float4*>(srec) + (size_t)idx * 5;
    r[0] = make_float4(wx[0], wx[1], wx[2], wx[3]);
    r[1] = make_float4(wy[0], wy[1], wy[2], wy[3]);
    r[2] = make_float4(wz[0], wz[1], wz[2], wz[3]);
    const float4* pw4 = reinterpret_cast<const float4*>(pw + (size_t)p * NCH);
    r[3] = pw4[0];
    r[4] = pw4[1];
}

// Sx(d) = sum_i wp[i] * wq[i-d], zero outside [0,3]; d in [-3,3].
__device__ __forceinline__ float corr4(float4 wp, float4 wq, int d) {
    float s0 = d == 0 ? wq.x : d == -1 ? wq.y : d == -2 ? wq.z : d == -3 ? wq.w : 0.0f;
    float s1 = d == 1 ? wq.x : d ==  0 ? wq.y : d == -1 ? wq.z : d == -2 ? wq.w : 0.0f;
    float s2 = d == 2 ? wq.x : d ==  1 ? wq.y : d ==  0 ? wq.z : d == -1 ? wq.w : 0.0f;
    float s3 = d == 3 ? wq.x : d ==  2 ? wq.y : d ==  1 ? wq.z : d ==  0 ? wq.w : 0.0f;
    return wp.x * s0 + wp.y * s1 + wp.z * s2 + wp.w * s3;
}

// One block per tile. Stage filtered candidates into LDS; Phase A: flat
// dense enumeration of (owned, cand) combos -> packed pair list via
// wave-aggregated ballot compaction; Phase B: dense eval of real pairs with
// LDS-atomic accumulation; write out.
__global__ __launch_bounds__(256) void pair_k(const int* __restrict__ offsets,
                                              const int* __restrict__ scell,
                                              const int* __restrict__ spid,
                                              const float* __restrict__ srec,
                                              float* __restrict__ out) {
    __shared__ int ccell[CMAX];
    __shared__ __align__(16) float crec[CMAX * REC];   // 25.6 KB
    __shared__ int plist[PMAX];                        // 10 KB
    __shared__ int ocellS[OMAX];
    __shared__ __align__(16) float orec[OMAX * 12];    // 6 KB (owned wx/wy/wz)
    __shared__ float acc[OMAX * 9];                    // 4.6 KB, stride-9
    __shared__ int nb0[27];
    __shared__ int nbase[28];
    __shared__ int ncand, npair;

    int b = blockIdx.x;
    int tx = b >> 8, ty = (b >> 4) & 15, tz = b & 15;
    int tid = threadIdx.x;
    int lane = tid & 63;
    int begin = offsets[b], end = offsets[b + 1];
    int nown = end - begin;
    if (nown == 0) return;  // uniform; no barrier crossed yet
    if (nown > OMAX) nown = OMAX;

    if (tid < 27) {
        int n = tid;
        int ox = n / 9 - 1, oy = (n / 3) % 3 - 1, oz = n % 3 - 1;
        int nt = ((((tx + ox) & 15) * NT + ((ty + oy) & 15)) * NT) + ((tz + oz) & 15);
        int b0 = offsets[nt];
        nb0[n] = b0;
        nbase[n] = offsets[nt + 1] - b0;  // count; scanned below
    }
    if (tid == 0) { ncand = 0; npair = 0; }
    __syncthreads();
    if (tid == 0) {
        int run = 0;
        #pragma unroll
        for (int n = 0; n < 27; ++n) { int c = nbase[n]; nbase[n] = run; run += c; }
        nbase[27] = run;
    }
    __syncthreads();
    int tc = nbase[27];

    // --- staging: zero acc, stage owned, stage filtered candidates ---
    for (int i = tid; i < nown * 9; i += 256) acc[i] = 0.0f;
    for (int i = tid; i < nown; i += 256) ocellS[i] = scell[begin + i];
    const float4* recs = reinterpret_cast<const float4*>(srec);
    {
        float4* od = reinterpret_cast<float4*>(orec);
        for (int i = tid; i < nown * 3; i += 256) {
            int p = i / 3, k = i - p * 3;
            od[p * 3 + k] = recs[(size_t)(begin + p) * 5 + k];
        }
    }
    int base_x = tx * TS - 3, base_y = ty * TS - 3, base_z = tz * TS - 3;
    for (int u0 = 0; u0 < tc; u0 += 256) {
        int u = u0 + tid;
        bool pass = false;
        int i = 0, c = 0;
        if (u < tc) {
            int lo = 0, hi = 27;
            while (hi - lo > 1) { int mid = (lo + hi) >> 1; if (nbase[mid] <= u) lo = mid; else hi = mid; }
            i = nb0[lo] + (u - nbase[lo]);
            c = scell[i];
            pass = (((c & 255)         - base_x) & 127) < 14
                && ((((c >> 8) & 255)  - base_y) & 127) < 14
                && ((((c >> 16) & 255) - base_z) & 127) < 14;
        }
        unsigned long long m = __ballot(pass);
        int cnt = __popcll(m);
        int kb = 0;
        if (lane == 0 && cnt) kb = atomicAdd(&ncand, cnt);
        kb = __shfl(kb, 0, 64);
        if (pass) {
            int k = kb + __popcll(m & ((1ull << lane) - 1ull));
            if (k < CMAX) {
                ccell[k] = c;
                const float4* r = recs + (size_t)i * 5;
                float4* d = reinterpret_cast<float4*>(crec + k * REC);
                d[0] = r[0]; d[1] = r[1]; d[2] = r[2]; d[3] = r[3]; d[4] = r[4];
            }
        }
    }
    __syncthreads();
    int nc = min(ncand, CMAX);

    // --- phase A: dense enumeration of nown*nc combos -> packed plist ---
    int tcp = nown * nc;
    for (int u0 = 0; u0 < tcp; u0 += 256) {
        int u = u0 + tid;
        bool pass = false;
        int p = 0, j = 0, dx = 0, dy = 0, dz = 0;
        if (u < tcp) {
            p = u / nc; j = u - p * nc;
            int pc = ocellS[p], qc = ccell[j];
            dx = (((qc & 255) - (pc & 255)) & 127);                 if (dx > 63) dx -= 128;
            dy = ((((qc >> 8) & 255) - ((pc >> 8) & 255)) & 127);   if (dy > 63) dy -= 128;
            dz = ((((qc >> 16) & 255) - ((pc >> 16) & 255)) & 127); if (dz > 63) dz -= 128;
            pass = (unsigned)(dx + 3) <= 6u && (unsigned)(dy + 3) <= 6u &&
                   (unsigned)(dz + 3) <= 6u;
        }
        unsigned long long m = __ballot(pass);
        int cnt = __popcll(m);
        int kb = 0;
        if (lane == 0 && cnt) kb = atomicAdd(&npair, cnt);
        kb = __shfl(kb, 0, 64);
        if (pass) {
            int k = kb + __popcll(m & ((1ull << lane) - 1ull));
            if (k < PMAX)
                plist[k] = (p << 18) | (j << 9) | ((dx + 3) << 6) | ((dy + 3) << 3) | (dz + 3);
        }
    }
    __syncthreads();
    int np = min(npair, PMAX);

    // --- phase B: dense pair evaluation ---
    for (int u = tid; u < np; u += 256) {
        int e = plist[u];
        int p = e >> 18, j = (e >> 9) & 511;
        int dx = ((e >> 6) & 7) - 3, dy = ((e >> 3) & 7) - 3, dz = (e & 7) - 3;
        const float4* q = reinterpret_cast<const float4*>(crec + j * REC);
        const float4* o = reinterpret_cast<const float4*>(orec + p * 12);
        float S = corr4(o[0], q[0], dx) * corr4(o[1], q[1], dy) * corr4(o[2], q[2], dz);
        float4 ch0 = q[3], ch1 = q[4];
        float* a = acc + p * 9;
        atomicAdd(a + 0, S * ch0.x);
        atomicAdd(a + 1, S * ch0.y);
        atomicAdd(a + 2, S * ch0.z);
        atomicAdd(a + 3, S * ch0.w);
        atomicAdd(a + 4, S * ch1.x);
        atomicAdd(a + 5, S * ch1.y);
        atomicAdd(a + 6, S * ch1.z);
        atomicAdd(a + 7, S * ch1.w);
    }
    __syncthreads();

    // --- write out ---
    for (int i = tid; i < nown * NCH; i += 256) {
        int p = i >> 3, c = i & 7;
        out[(size_t)spid[begin + p] * NCH + c] = acc[p * 9 + c];
    }
}

extern "C" void kernel_launch(void* const* d_in, const int* in_sizes, int n_in,
                              void* d_out, int out_size, void* d_ws, size_t ws_size,
                              hipStream_t stream) {
    const float* pos  = (const float*)d_in[0];
    const float* pw   = (const float*)d_in[1];
    const float* cell = (const float*)d_in[2];
    float* out = (float*)d_out;

    float* srec   = (float*)d_ws;                 // NPTS*20 floats (16B aligned)
    int*   scell  = (int*)(srec + (size_t)NPTS * REC);
    int*   spid   = scell + NPTS;
    int*   counts = spid + NPTS;
    int*   cursor = counts + NTILES;
    int*   offsets = cursor + NTILES;             // NTILES+1

    hipMemsetAsync(counts, 0, 2 * NTILES * sizeof(int), stream);

    int pblocks = (NPTS + 255) / 256;
    hist_k<<<pblocks, 256, 0, stream>>>(pos, cell, counts);
    scan_k<<<1, 256, 0, stream>>>(counts, offsets);
    reorder_k<<<pblocks, 256, 0, stream>>>(pos, pw, cell, offsets, cursor,
                                           scell, spid, srec);
    pair_k<<<NTILES, 256, 0, stream>>>(offsets, scell, spid, srec, out);
}

// Round 6
// 146.983 us; speedup vs baseline: 1.4042x; 1.4042x over previous
//
#include <hip/hip_runtime.h>

static constexpr int NXC   = 128;              // cells per axis
static constexpr int NPTS  = 100000;
static constexpr int NCH   = 8;
static constexpr int TS    = 4;                // tile cells/axis
static constexpr int NT    = 32;               // tiles/axis
static constexpr int NTILES = NT * NT * NT;    // 32768
static constexpr int REC   = 20;               // floats per global particle record
static constexpr int RECL  = 12;               // staged LDS floats (wx,wy,wz)
static constexpr int HALO  = TS + 6;           // 10 cells
static constexpr int CMAX  = 128;              // max candidates (E≈48, +11σ)
static constexpr int OMAX  = 32;               // max owned (E≈3)

// P3M order-4 per-axis weights, x in [-1/2, 1/2]
__device__ __forceinline__ void axis_weights(float x, float w[4]) {
    float x2 = x * x, x3 = x2 * x;
    const float c = 1.0f / 48.0f;
    w[0] = c * (1.0f  - 6.0f  * x + 12.0f * x2 - 8.0f  * x3);
    w[1] = c * (23.0f - 30.0f * x - 12.0f * x2 + 24.0f * x3);
    w[2] = c * (23.0f + 30.0f * x - 12.0f * x2 - 24.0f * x3);
    w[3] = c * (1.0f  + 6.0f  * x + 12.0f * x2 + 8.0f  * x3);
}

// Mesh-scaled fractional coords (identical FP sequence in every kernel).
__device__ __forceinline__ void mesh_coords(const float* __restrict__ pos,
                                            const float* __restrict__ cell,
                                            int p, float& rx, float& ry, float& rz) {
    float a = cell[0], b = cell[1], c = cell[2];
    float d = cell[3], e = cell[4], f = cell[5];
    float g = cell[6], h = cell[7], i9 = cell[8];
    float c00 = e * i9 - f * h, c01 = f * g - d * i9, c02 = d * h - e * g;
    float c10 = c * h - b * i9, c11 = a * i9 - c * g, c12 = b * g - a * h;
    float c20 = b * f - c * e,  c21 = c * d - a * f,  c22 = a * e - b * d;
    float det = a * c00 + b * c01 + c * c02;
    float s = 128.0f / det;
    float p0 = pos[p * 3 + 0], p1 = pos[p * 3 + 1], p2 = pos[p * 3 + 2];
    rx = s * (p0 * c00 + p1 * c01 + p2 * c02);
    ry = s * (p0 * c10 + p1 * c11 + p2 * c12);
    rz = s * (p0 * c20 + p1 * c21 + p2 * c22);
}

__global__ __launch_bounds__(256) void hist_k(const float* __restrict__ pos,
                                              const float* __restrict__ cell,
                                              int* __restrict__ counts) {
    int p = blockIdx.x * 256 + threadIdx.x;
    if (p >= NPTS) return;
    float rx, ry, rz;
    mesh_coords(pos, cell, p, rx, ry, rz);
    int ix = ((int)floorf(rx)) & (NXC - 1);
    int iy = ((int)floorf(ry)) & (NXC - 1);
    int iz = ((int)floorf(rz)) & (NXC - 1);
    int tile = ((ix >> 2) * NT + (iy >> 2)) * NT + (iz >> 2);
    atomicAdd(counts + tile, 1);
}

// exclusive prefix sum over 32768 counts -> offsets[0..32768]
__global__ __launch_bounds__(1024) void scan_k(const int* __restrict__ counts,
                                               int* __restrict__ offsets) {
    __shared__ int sc[1024];
    int tid = threadIdx.x;
    int c[32];
    int s = 0;
    #pragma unroll
    for (int j = 0; j < 32; ++j) { c[j] = counts[tid * 32 + j]; s += c[j]; }
    sc[tid] = s;
    __syncthreads();
    for (int d = 1; d < 1024; d <<= 1) {
        int v = (tid >= d) ? sc[tid - d] : 0;
        __syncthreads();
        sc[tid] += v;
        __syncthreads();
    }
    int run = sc[tid] - s;
    #pragma unroll
    for (int j = 0; j < 32; ++j) { offsets[tid * 32 + j] = run; run += c[j]; }
    if (tid == 1023) offsets[NTILES] = run;
}

// Bin particles by tile; emit packed cell, original pid, and a 5-float4 record:
// [wx0..3][wy0..3][wz0..3][ch0..3][ch4..7]
__global__ __launch_bounds__(256) void reorder_k(const float* __restrict__ pos,
                                                 const float* __restrict__ pw,
                                                 const float* __restrict__ cell,
                                                 const int* __restrict__ offsets,
                                                 int* __restrict__ cursor,
                                                 int* __restrict__ scell,
                                                 int* __restrict__ spid,
                                                 float* __restrict__ srec) {
    int p = blockIdx.x * 256 + threadIdx.x;
    if (p >= NPTS) return;
    float rx, ry, rz;
    mesh_coords(pos, cell, p, rx, ry, rz);
    float fx = floorf(rx), fy = floorf(ry), fz = floorf(rz);
    int ix = ((int)fx) & (NXC - 1), iy = ((int)fy) & (NXC - 1), iz = ((int)fz) & (NXC - 1);
    int tile = ((ix >> 2) * NT + (iy >> 2)) * NT + (iz >> 2);
    int slot = atomicAdd(cursor + tile, 1);
    int idx = offsets[tile] + slot;
    scell[idx] = ix | (iy << 8) | (iz << 16);
    spid[idx] = p;
    float wx[4], wy[4], wz[4];
    axis_weights(rx - fx - 0.5f, wx);
    axis_weights(ry - fy - 0.5f, wy);
    axis_weights(rz - fz - 0.5f, wz);
    float4* r = reinterpret_cast<float4*>(srec) + (size_t)idx * 5;
    r[0] = make_float4(wx[0], wx[1], wx[2], wx[3]);
    r[1] = make_float4(wy[0], wy[1], wy[2], wy[3]);
    r[2] = make_float4(wz[0], wz[1], wz[2], wz[3]);
    const float4* pw4 = reinterpret_cast<const float4*>(pw + (size_t)p * NCH);
    r[3] = pw4[0];
    r[4] = pw4[1];
}

// Sx(d) = sum_i wp[i] * wq[i-d], zero outside [0,3]; d in [-3,3].
__device__ __forceinline__ float corr4(float4 wp, float4 wq, int d) {
    float s0 = d == 0 ? wq.x : d == -1 ? wq.y : d == -2 ? wq.z : d == -3 ? wq.w : 0.0f;
    float s1 = d == 1 ? wq.x : d ==  0 ? wq.y : d == -1 ? wq.z : d == -2 ? wq.w : 0.0f;
    float s2 = d == 2 ? wq.x : d ==  1 ? wq.y : d ==  0 ? wq.z : d == -1 ? wq.w : 0.0f;
    float s3 = d == 3 ? wq.x : d ==  2 ? wq.y : d ==  1 ? wq.z : d ==  0 ? wq.w : 0.0f;
    return wp.x * s0 + wp.y * s1 + wp.z * s2 + wp.w * s3;
}

// One wave per tile (TS=4). Stage filtered candidates' weights in LDS; eval
// with 16 lanes per (owned, 16-candidate chunk) unit, register accumulation,
// shfl reduce, one conflict-free LDS atomic per unit; channels read from L2.
__global__ __launch_bounds__(64) void pair_k(const int* __restrict__ offsets,
                                             const int* __restrict__ scell,
                                             const int* __restrict__ spid,
                                             const float* __restrict__ srec,
                                             float* __restrict__ out) {
    __shared__ int ccell[CMAX];
    __shared__ int cidx[CMAX];
    __shared__ __align__(16) float crec[CMAX * RECL];  // 6 KB
    __shared__ int ocellS[OMAX];
    __shared__ int opid[OMAX];
    __shared__ __align__(16) float orec[OMAX * 12];
    __shared__ float acc[OMAX * 9];
    __shared__ int nb0[27];
    __shared__ int nbase[28];
    __shared__ int ncand;

    int b = blockIdx.x;
    int tx = b >> 10, ty = (b >> 5) & 31, tz = b & 31;
    int tid = threadIdx.x;
    int begin = offsets[b], end = offsets[b + 1];
    int nown = end - begin;
    if (nown == 0) return;  // whole wave exits together
    if (nown > OMAX) nown = OMAX;  // statistically unreachable

    if (tid < 27) {
        int ox = tid / 9 - 1, oy = (tid / 3) % 3 - 1, oz = tid % 3 - 1;
        int nt = ((((tx + ox) & 31) * NT + ((ty + oy) & 31)) * NT) + ((tz + oz) & 31);
        nb0[tid] = offsets[nt];
        nbase[tid] = offsets[nt + 1] - nb0[tid];
    }
    if (tid == 0) ncand = 0;
    __syncthreads();
    if (tid == 0) {
        int run = 0;
        #pragma unroll
        for (int n = 0; n < 27; ++n) { int c = nbase[n]; nbase[n] = run; run += c; }
        nbase[27] = run;
    }
    __syncthreads();
    int tc = nbase[27];

    // stage owned + zero acc
    for (int i = tid; i < nown * 9; i += 64) acc[i] = 0.0f;
    for (int i = tid; i < nown; i += 64) {
        ocellS[i] = scell[begin + i];
        opid[i] = spid[begin + i];
    }
    const float4* recs = reinterpret_cast<const float4*>(srec);
    for (int i = tid; i < nown * 3; i += 64) {
        int p = i / 3, k = i - p * 3;
        reinterpret_cast<float4*>(orec)[p * 3 + k] = recs[(size_t)(begin + p) * 5 + k];
    }

    // stage filtered candidates (weights only)
    int base_x = tx * TS - 3, base_y = ty * TS - 3, base_z = tz * TS - 3;
    for (int u0 = 0; u0 < tc; u0 += 64) {
        int u = u0 + tid;
        bool pass = false;
        int i = 0, c = 0;
        if (u < tc) {
            int lo = 0, hi = 27;
            while (hi - lo > 1) { int mid = (lo + hi) >> 1; if (nbase[mid] <= u) lo = mid; else hi = mid; }
            i = nb0[lo] + (u - nbase[lo]);
            c = scell[i];
            pass = (((c & 255)         - base_x) & 127) < HALO
                && ((((c >> 8) & 255)  - base_y) & 127) < HALO
                && ((((c >> 16) & 255) - base_z) & 127) < HALO;
        }
        unsigned long long m = __ballot(pass);
        int kb = 0;
        if (tid == 0 && m) kb = atomicAdd(&ncand, __popcll(m));
        kb = __shfl(kb, 0, 64);
        if (pass) {
            int k = kb + __popcll(m & ((1ull << tid) - 1ull));
            if (k < CMAX) {
                ccell[k] = c;
                cidx[k] = i;
                const float4* r = recs + (size_t)i * 5;
                float4* d = reinterpret_cast<float4*>(crec + k * RECL);
                d[0] = r[0]; d[1] = r[1]; d[2] = r[2];
            }
        }
    }
    __syncthreads();
    int nc = min(ncand, CMAX);

    // eval: unit = (owned p, 16-candidate chunk); 4 groups of 16 lanes
    int sub = tid & 15, grp = tid >> 4;
    int nchunk = (nc + 15) >> 4;
    int units = nown * nchunk;
    for (int u = grp; u < units; u += 4) {
        int p = u / nchunk, chunk = u - p * nchunk;
        int j = chunk * 16 + sub;
        float a[8] = {0, 0, 0, 0, 0, 0, 0, 0};
        if (j < nc) {
            int qc = ccell[j], pc = ocellS[p];
            int dx = (((qc & 255) - (pc & 255)) & 127);                 if (dx > 63) dx -= 128;
            int dy = ((((qc >> 8) & 255) - ((pc >> 8) & 255)) & 127);   if (dy > 63) dy -= 128;
            int dz = ((((qc >> 16) & 255) - ((pc >> 16) & 255)) & 127); if (dz > 63) dz -= 128;
            if ((unsigned)(dx + 3) <= 6u && (unsigned)(dy + 3) <= 6u &&
                (unsigned)(dz + 3) <= 6u) {
                const float4* o = reinterpret_cast<const float4*>(orec + p * 12);
                const float4* q = reinterpret_cast<const float4*>(crec + j * RECL);
                float S = corr4(o[0], q[0], dx) * corr4(o[1], q[1], dy) *
                          corr4(o[2], q[2], dz);
                const float4* g = recs + (size_t)cidx[j] * 5 + 3;  // channels from L2
                float4 ch0 = g[0], ch1 = g[1];
                a[0] = S * ch0.x; a[1] = S * ch0.y; a[2] = S * ch0.z; a[3] = S * ch0.w;
                a[4] = S * ch1.x; a[5] = S * ch1.y; a[6] = S * ch1.z; a[7] = S * ch1.w;
            }
        }
        #pragma unroll
        for (int m2 = 1; m2 <= 8; m2 <<= 1) {
            #pragma unroll
            for (int c2 = 0; c2 < 8; ++c2) a[c2] += __shfl_xor(a[c2], m2, 64);
        }
        if (sub < 8) {
            float v = sub == 0 ? a[0] : sub == 1 ? a[1] : sub == 2 ? a[2] :
                      sub == 3 ? a[3] : sub == 4 ? a[4] : sub == 5 ? a[5] :
                      sub == 6 ? a[6] : a[7];
            atomicAdd(&acc[p * 9 + sub], v);  // distinct addresses across lanes
        }
    }
    __syncthreads();

    for (int i = tid; i < nown * NCH; i += 64) {
        int p = i >> 3, c = i & 7;
        out[(size_t)opid[p] * NCH + c] = acc[p * 9 + c];
    }
}

extern "C" void kernel_launch(void* const* d_in, const int* in_sizes, int n_in,
                              void* d_out, int out_size, void* d_ws, size_t ws_size,
                              hipStream_t stream) {
    const float* pos  = (const float*)d_in[0];
    const float* pw   = (const float*)d_in[1];
    const float* cell = (const float*)d_in[2];
    float* out = (float*)d_out;

    float* srec   = (float*)d_ws;                 // NPTS*20 floats (16B aligned)
    int*   scell  = (int*)(srec + (size_t)NPTS * REC);
    int*   spid   = scell + NPTS;
    int*   counts = spid + NPTS;
    int*   cursor = counts + NTILES;
    int*   offsets = cursor + NTILES;             // NTILES+1

    hipMemsetAsync(counts, 0, 2 * NTILES * sizeof(int), stream);

    int pblocks = (NPTS + 255) / 256;
    hist_k<<<pblocks, 256, 0, stream>>>(pos, cell, counts);
    scan_k<<<1, 1024, 0, stream>>>(counts, offsets);
    reorder_k<<<pblocks, 256, 0, stream>>>(pos, pw, cell, offsets, cursor,
                                           scell, spid, srec);
    pair_k<<<NTILES, 64, 0, stream>>>(offsets, scell, spid, srec, out);
}